// Round 6
// baseline (831.314 us; speedup 1.0000x reference)
//
#include <hip/hip_runtime.h>
#include <hip/hip_bf16.h>

typedef __attribute__((ext_vector_type(8))) short short8;   // 8 bf16 in 4 VGPRs
typedef __attribute__((ext_vector_type(4))) float f32x4;

#define N_HEAD 16
#define DMODEL 1024
#define LV 2048
#define LQ 2048
#define BATCH 2
#define HEAD_DIM 64

template <int N> struct IC { static constexpr int v = N; };

__device__ inline ushort f2bf(float f) {
    union { float f; unsigned u; } v; v.f = f;
    unsigned r = v.u + 0x7fffu + ((v.u >> 16) & 1u);   // RNE
    return (ushort)(r >> 16);
}
__device__ inline float bf2f(ushort h) {
    union { unsigned u; float f; } v; v.u = ((unsigned)h) << 16;
    return v.f;
}

// ---------------- cast f32 -> bf16 (same layout) ----------------
__global__ __launch_bounds__(256) void cast_bf16(const float* __restrict__ src,
                                                 ushort* __restrict__ dst, int n) {
    int i = (blockIdx.x * 256 + threadIdx.x) * 4;
    if (i < n) {
        float4 v = *(const float4*)(src + i);
        ushort4 o;
        o.x = f2bf(v.x); o.y = f2bf(v.y); o.z = f2bf(v.z); o.w = f2bf(v.w);
        *(ushort4*)(dst + i) = o;
    }
}

// ---------------- transpose + cast: src[z][R][C] f32 -> dst[z][C][R] bf16 ----
__global__ __launch_bounds__(256) void transpose_cast(const float* __restrict__ src,
                                                      ushort* __restrict__ dst,
                                                      int R, int C) {
    __shared__ float t[32][33];
    size_t zoff = (size_t)blockIdx.z * R * C;
    int c0 = blockIdx.x * 32, r0 = blockIdx.y * 32;
    int tx = threadIdx.x, ty = threadIdx.y;
#pragma unroll
    for (int i = 0; i < 4; ++i)
        t[ty + i * 8][tx] = src[zoff + (size_t)(r0 + ty + i * 8) * C + c0 + tx];
    __syncthreads();
#pragma unroll
    for (int i = 0; i < 4; ++i)
        dst[zoff + (size_t)(c0 + ty + i * 8) * R + r0 + tx] = f2bf(t[tx][ty + i * 8]);
}

// ---------------- 256x256 batched GEMM, within-wave pipelined ----------------
// C[z] = (relu)(A[z] @ B[z]^T + bias).  BK=32, 4 LDS K-tile buffers (prefetch
// depth 3), 8 waves (2Mx4N).  ONE barrier per K-tile; double-buffered register
// fragments so ds_read(t+1) overlaps MFMA(t) within each wave.
// RACE FIX vs r5: counted vmcnt moved BEFORE the barrier (vmcnt is per-wave;
// reads of tile t+1 must follow a barrier that every wave reached only after
// draining its own tile-t+1 stage loads).  lgkmcnt(12)+sched_barrier(0) pin
// tile-t ds_read completion before the barrier (stage-overwrite safety, #18).
template <bool RELU>
__global__ __launch_bounds__(512, 2) void gemm256(
    const ushort* __restrict__ A, const ushort* __restrict__ B,
    ushort* __restrict__ Cout, const float* __restrict__ bias,
    int K,
    long sA_b, long sA_h, long sB_b, long sB_h, long sC_z, int ldc, long sBias_h)
{
    // [buf(4)][op(2)] x 16 KiB = 128 KiB.  op region: [half(2)][8 subtiles][1 KiB]
    __shared__ __align__(16) char smem[131072];

    const int z = blockIdx.z, b = z & 1, h = z >> 1;
    A += (size_t)b * sA_b + (size_t)h * sA_h;
    B += (size_t)b * sB_b + (size_t)h * sB_h;
    const float* biasp = bias ? bias + (size_t)h * sBias_h : nullptr;

    const int bm0 = blockIdx.y * 256;
    const int bn0 = blockIdx.x * 256;
    const int T = threadIdx.x;
    const int lane = T & 63, wid = T >> 6;
    const int wr = wid >> 2, wc = wid & 3;          // wave -> (2 x 4) grid
    const int fr = lane & 15, fq = lane >> 4;
    // byte offset of this lane's fragment within a 1 KiB subtile (swizzled read)
    const int laneoff = fr * 64 + ((fq * 16) ^ ((fr >> 3) << 5));

    // staging: thread T owns LDS bytes [T*16, T*16+16) of each 8 KiB half;
    // global source pre-swizzled so (linear LDS dest, swizzled read) match.
    const int s_fr  = (T >> 2) & 15;
    const int s_csw = ((T & 3) * 16) ^ ((s_fr >> 3) << 5);   // pre-swizzled col
    const int s_rh  = ((T >> 6) << 4) + s_fr;                // row within half
    const ushort* gA = A + (size_t)(bm0 + s_rh) * K + (s_csw >> 1);
    const ushort* gB = B + (size_t)(bn0 + s_rh) * K + (s_csw >> 1);
    char* smc = smem;

    const int nt = K >> 5;      // K-tiles of 32 (even, >= 8 here)

    auto stage = [&](int op, int half, int kt) {
        const ushort* src = (op ? gB : gA) + ((size_t)half * 128) * K + (size_t)kt * 32;
        char* dst = smc + (((kt & 3) * 2 + op) << 14) + (half << 13) + (T << 4);
        __builtin_amdgcn_global_load_lds(
            (const __attribute__((address_space(1))) void*)src,
            (__attribute__((address_space(3))) void*)dst, 16, 0, 0);
    };
    auto stage4 = [&](int kt) {
        stage(0, 0, kt); stage(0, 1, kt); stage(1, 0, kt); stage(1, 1, kt);
    };

    struct Frags { short8 a[8]; short8 bb[4]; };
    auto ldfrag = [&](int t, Frags& F) {
        const char* sA = smc + (((t & 3) * 2 + 0) << 14) + wr * 8192 + laneoff;
        const char* sB = smc + (((t & 3) * 2 + 1) << 14) + wc * 4096 + laneoff;
#pragma unroll
        for (int m = 0; m < 8; ++m) F.a[m] = *(const short8*)(sA + m * 1024);
#pragma unroll
        for (int n = 0; n < 4; ++n) F.bb[n] = *(const short8*)(sB + n * 1024);
    };

    f32x4 acc[8][4];
#pragma unroll
    for (int m = 0; m < 8; ++m)
#pragma unroll
        for (int n = 0; n < 4; ++n)
#pragma unroll
            for (int j = 0; j < 4; ++j) acc[m][n][j] = 0.f;

    auto mfma32 = [&](Frags& F) {
        __builtin_amdgcn_s_setprio(1);
#pragma unroll
        for (int m = 0; m < 8; ++m)
#pragma unroll
            for (int n = 0; n < 4; ++n)
                acc[m][n] = __builtin_amdgcn_mfma_f32_16x16x32_bf16(
                    F.a[m], F.bb[n], acc[m][n], 0, 0, 0);
        __builtin_amdgcn_s_setprio(0);
    };

    // one K-tile: read tile t+1 frags (landed: prev barrier), stage t+3,
    // MFMA tile t, then {pin tile-t reads, counted vmcnt for t+2} BEFORE barrier.
    auto step = [&](int t, Frags& rd, Frags& mm, auto VM, auto DOSTAGE, auto DOREAD) {
        constexpr int vm = decltype(VM)::v;
        if constexpr (decltype(DOREAD)::v)  ldfrag(t + 1, rd);
        if constexpr (decltype(DOSTAGE)::v) stage4(t + 3);
        mfma32(mm);
        __builtin_amdgcn_sched_barrier(0);
        if constexpr (vm == 4)
            asm volatile("s_waitcnt vmcnt(4) lgkmcnt(12)" ::: "memory");
        else if constexpr (vm == 0)
            asm volatile("s_waitcnt vmcnt(0) lgkmcnt(12)" ::: "memory");
        else
            asm volatile("s_waitcnt lgkmcnt(12)" ::: "memory");
        asm volatile("s_barrier" ::: "memory");
    };

    // prologue: stage tiles 0,1,2; drain tiles 0 AND 1 (all waves) pre-barrier
    stage4(0); stage4(1); stage4(2);
    asm volatile("s_waitcnt vmcnt(4)" ::: "memory");
    asm volatile("s_barrier" ::: "memory");
    Frags fA, fB;
    ldfrag(0, fA);

    for (int t = 0; t < nt - 4; t += 2) {
        step(t,     fB, fA, IC<4>{}, IC<1>{}, IC<1>{});
        step(t + 1, fA, fB, IC<4>{}, IC<1>{}, IC<1>{});
    }
    // tail (parity: nt even)
    step(nt - 4, fB, fA, IC<4>{},  IC<1>{}, IC<1>{});   // stage nt-1; drain nt-2
    step(nt - 3, fA, fB, IC<0>{},  IC<0>{}, IC<1>{});   // drain nt-1
    step(nt - 2, fB, fA, IC<-1>{}, IC<0>{}, IC<1>{});   // read nt-1
    step(nt - 1, fA, fB, IC<-1>{}, IC<0>{}, IC<0>{});   // last MFMA

    // epilogue: C[row = m*16 + fq*4 + j][col = n*16 + fr]  (m89/m91-verified)
    ushort* C = Cout + (size_t)z * sC_z;
    const int row0 = bm0 + wr * 128;
    const int col0 = bn0 + wc * 64;
#pragma unroll
    for (int n = 0; n < 4; ++n) {
        const int c = col0 + n * 16 + fr;
        const float bvv = biasp ? biasp[c] : 0.f;
#pragma unroll
        for (int m = 0; m < 8; ++m) {
            const int r = row0 + m * 16 + fq * 4;
#pragma unroll
            for (int j = 0; j < 4; ++j) {
                float val = acc[m][n][j] + bvv;
                if (RELU) val = fmaxf(val, 0.f);
                C[(size_t)(r + j) * ldc + c] = f2bf(val);
            }
        }
    }
}

// ---------------- in-place LayerNorm over last dim (1024) of agg bf16 --------
__global__ __launch_bounds__(256) void ln_kernel(ushort* __restrict__ agg,
                                                 const float* __restrict__ gamma,
                                                 const float* __restrict__ beta) {
    const int wid = threadIdx.x >> 6, lane = threadIdx.x & 63;
    const size_t row = (size_t)blockIdx.x * 4 + wid;
    const int h = (int)(row >> 12);
    ushort* p = agg + row * 1024 + lane * 16;
    short8 r0 = *(const short8*)p;
    short8 r1 = *(const short8*)(p + 8);
    float x[16];
#pragma unroll
    for (int j = 0; j < 8; ++j) { x[j] = bf2f((ushort)r0[j]); x[8 + j] = bf2f((ushort)r1[j]); }
    float s = 0.f, s2 = 0.f;
#pragma unroll
    for (int j = 0; j < 16; ++j) { s += x[j]; s2 += x[j] * x[j]; }
    for (int o = 1; o < 64; o <<= 1) {
        s  += __shfl_xor(s,  o, 64);
        s2 += __shfl_xor(s2, o, 64);
    }
    float mu  = s * (1.0f / 1024.0f);
    float var = s2 * (1.0f / 1024.0f) - mu * mu;
    float rs  = rsqrtf(fmaxf(var, 0.f) + 1e-5f);
    const float* g  = gamma + (size_t)h * 1024 + lane * 16;
    const float* bt = beta  + (size_t)h * 1024 + lane * 16;
    short8 o0, o1;
#pragma unroll
    for (int j = 0; j < 8; ++j) {
        o0[j] = (short)f2bf((x[j]     - mu) * rs * g[j]     + bt[j]);
        o1[j] = (short)f2bf((x[8 + j] - mu) * rs * g[8 + j] + bt[8 + j]);
    }
    *(short8*)p = o0;
    *(short8*)(p + 8) = o1;
}

// ---------------- projection: out[b][q][(h0+h)*64+e] = normed[z] @ WpT[h]^T + bp
__global__ __launch_bounds__(256) void proj_kernel(const ushort* __restrict__ normed,
                                                   const ushort* __restrict__ WpT,
                                                   const float* __restrict__ bp,
                                                   float* __restrict__ out,
                                                   int h_base) {
    const int z = blockIdx.y, b = z & 1, h = z >> 1;
    const int hg = h_base + h;
    const int wid = threadIdx.x >> 6, lane = threadIdx.x & 63;
    const int fr = lane & 15, fq = lane >> 4;
    const int m0 = (blockIdx.x * 4 + wid) * 16;

    const ushort* Abase = normed + ((size_t)z * 2048 + m0 + fr) * 1024 + fq * 8;
    const ushort* Bbase = WpT + (size_t)hg * 64 * 1024 + (size_t)fr * 1024 + fq * 8;

    f32x4 acc[4];
#pragma unroll
    for (int n = 0; n < 4; ++n)
#pragma unroll
        for (int j = 0; j < 4; ++j) acc[n][j] = 0.f;

    for (int kt = 0; kt < 32; ++kt) {
        short8 a = *(const short8*)(Abase + kt * 32);
#pragma unroll
        for (int n = 0; n < 4; ++n) {
            short8 bb = *(const short8*)(Bbase + n * 16 * 1024 + kt * 32);
            acc[n] = __builtin_amdgcn_mfma_f32_16x16x32_bf16(a, bb, acc[n], 0, 0, 0);
        }
    }
#pragma unroll
    for (int n = 0; n < 4; ++n) {
        int c = hg * 64 + n * 16 + fr;
        float bvv = bp[hg * 64 + n * 16 + fr];
#pragma unroll
        for (int j = 0; j < 4; ++j)
            out[(size_t)b * 2048 * 1024 + (size_t)(m0 + fq * 4 + j) * 1024 + c] =
                acc[n][j] + bvv;
    }
}

extern "C" void kernel_launch(void* const* d_in, const int* in_sizes, int n_in,
                              void* d_out, int out_size, void* d_ws, size_t ws_size,
                              hipStream_t stream) {
    const float* v     = (const float*)d_in[0];
    const float* q     = (const float*)d_in[1];
    const float* Wa    = (const float*)d_in[2];
    const float* ba    = (const float*)d_in[3];
    const float* gamma = (const float*)d_in[4];
    const float* beta  = (const float*)d_in[5];
    const float* Wp    = (const float*)d_in[6];
    const float* bp    = (const float*)d_in[7];
    float* out = (float*)d_out;

    const size_t MB = 1ull << 20;
    char* ws = (char*)d_ws;
    ushort* qbf = (ushort*)(ws);                 //  8 MiB
    ushort* vT  = (ushort*)(ws + 8 * MB);        //  8 MiB
    ushort* WpT = (ushort*)(ws + 16 * MB);       //  2 MiB
    int NH = 1;
    {
        const int cands[5] = {16, 8, 4, 2, 1};
        for (int i = 0; i < 5; ++i) {
            if ((size_t)(18 + 28 * cands[i]) * MB <= ws_size) { NH = cands[i]; break; }
        }
    }
    ushort* WaT_c  = (ushort*)(ws + 18 * MB);
    ushort* attn_c = (ushort*)(ws + (18 + (size_t)4 * NH) * MB);
    ushort* agg_c  = (ushort*)(ws + (18 + (size_t)20 * NH) * MB);

    dim3 tb(32, 8);
    cast_bf16<<<4096, 256, 0, stream>>>(q, qbf, BATCH * LQ * DMODEL);
    transpose_cast<<<dim3(DMODEL / 32, LV / 32, BATCH), tb, 0, stream>>>(v, vT, LV, DMODEL);
    transpose_cast<<<dim3(HEAD_DIM / 32, DMODEL / 32, N_HEAD), tb, 0, stream>>>(Wp, WpT, DMODEL, HEAD_DIM);

    for (int h0 = 0; h0 < N_HEAD; h0 += NH) {
        transpose_cast<<<dim3(LV / 32, DMODEL / 32, NH), tb, 0, stream>>>(
            Wa + (size_t)h0 * DMODEL * LV, WaT_c, DMODEL, LV);

        // GEMM1: attn[z] = relu(q[b] @ WaT[h]^T + ba[h0+h]), M=2048 N=2048 K=1024
        gemm256<true><<<dim3(LV / 256, LQ / 256, NH * 2), 512, 0, stream>>>(
            qbf, WaT_c, attn_c, ba + (size_t)h0 * LV, DMODEL,
            (long)LQ * DMODEL, 0L,
            0L, (long)LV * DMODEL,
            (long)LQ * LV, LV, (long)LV);

        // GEMM2: agg[z] = attn[z] @ vT[b]^T, M=2048 N=1024 K=2048
        gemm256<false><<<dim3(DMODEL / 256, LQ / 256, NH * 2), 512, 0, stream>>>(
            attn_c, vT, agg_c, nullptr, LV,
            (long)LQ * LV, (long)2 * LQ * LV,
            (long)DMODEL * LV, 0L,
            (long)LQ * DMODEL, DMODEL, 0L);

        ln_kernel<<<(NH * 2 * LQ) / 4, 256, 0, stream>>>(
            agg_c, gamma + (size_t)h0 * DMODEL, beta + (size_t)h0 * DMODEL);

        proj_kernel<<<dim3(LQ / 64, NH * 2), 256, 0, stream>>>(
            agg_c, WpT, bp, out, h0);
    }
}

// Round 7
// 817.036 us; speedup vs baseline: 1.0175x; 1.0175x over previous
//
#include <hip/hip_runtime.h>
#include <hip/hip_bf16.h>

typedef __attribute__((ext_vector_type(8))) short short8;   // 8 bf16 in 4 VGPRs
typedef __attribute__((ext_vector_type(4))) float f32x4;

#define N_HEAD 16
#define DMODEL 1024
#define LV 2048
#define LQ 2048
#define BATCH 2
#define HEAD_DIM 64

template <int N> struct IC { static constexpr int v = N; };

__device__ inline ushort f2bf(float f) {
    union { float f; unsigned u; } v; v.f = f;
    unsigned r = v.u + 0x7fffu + ((v.u >> 16) & 1u);   // RNE
    return (ushort)(r >> 16);
}
__device__ inline float bf2f(ushort h) {
    union { unsigned u; float f; } v; v.u = ((unsigned)h) << 16;
    return v.f;
}

// ---------------- cast f32 -> bf16 (same layout) ----------------
__global__ __launch_bounds__(256) void cast_bf16(const float* __restrict__ src,
                                                 ushort* __restrict__ dst, int n) {
    int i = (blockIdx.x * 256 + threadIdx.x) * 4;
    if (i < n) {
        float4 v = *(const float4*)(src + i);
        ushort4 o;
        o.x = f2bf(v.x); o.y = f2bf(v.y); o.z = f2bf(v.z); o.w = f2bf(v.w);
        *(ushort4*)(dst + i) = o;
    }
}

// ---------------- transpose + cast: src[z][R][C] f32 -> dst[z][C][R] bf16 ----
__global__ __launch_bounds__(256) void transpose_cast(const float* __restrict__ src,
                                                      ushort* __restrict__ dst,
                                                      int R, int C) {
    __shared__ float t[32][33];
    size_t zoff = (size_t)blockIdx.z * R * C;
    int c0 = blockIdx.x * 32, r0 = blockIdx.y * 32;
    int tx = threadIdx.x, ty = threadIdx.y;
#pragma unroll
    for (int i = 0; i < 4; ++i)
        t[ty + i * 8][tx] = src[zoff + (size_t)(r0 + ty + i * 8) * C + c0 + tx];
    __syncthreads();
#pragma unroll
    for (int i = 0; i < 4; ++i)
        dst[zoff + (size_t)(c0 + ty + i * 8) * R + r0 + tx] = f2bf(t[tx][ty + i * 8]);
}

// -------- 256x256 batched GEMM, 4-phase/K64 quadrant interleave (m201 port) --
// C[z] = (relu)(A[z] @ B[z]^T + bias).  BK=64 split as 2 kh-halves of 32.
// LDS: 2 step-bufs x [A(2kh x 16KB) | B(2kh x 16KB)] = 128 KiB.
// 8 waves (2M x 4N), per-wave C 128x64, acc[8][4] f32x4.
// Per step s: phases P0(mh0,k0) P1(mh1,k0) P2(mh0,k1) P3(mh1,k1); each phase:
//   {4-8 ds_read_b128; stage ONE half-tile of s+1; BAR; lgkmcnt(0)+SB(0);
//    setprio(1); 16 MFMA; setprio(0); SB(0); [vmcnt(4) at P1/P3]; BAR}
// Half-tile stage stream [A.k0,B.k0,A.k1,B.k1]: vmcnt(4) leaves exactly the 2
// newest half-tiles in flight -> next phases' data always landed, never drain-0.
template <bool RELU>
__global__ __launch_bounds__(512, 2) void gemm256(
    const ushort* __restrict__ A, const ushort* __restrict__ B,
    ushort* __restrict__ Cout, const float* __restrict__ bias,
    int K,
    long sA_b, long sA_h, long sB_b, long sB_h, long sC_z, int ldc, long sBias_h)
{
    __shared__ __align__(16) char smem[131072];

    const int z = blockIdx.z, b = z & 1, h = z >> 1;
    A += (size_t)b * sA_b + (size_t)h * sA_h;
    B += (size_t)b * sB_b + (size_t)h * sB_h;
    const float* biasp = bias ? bias + (size_t)h * sBias_h : nullptr;

    const int bm0 = blockIdx.y * 256;
    const int bn0 = blockIdx.x * 256;
    const int T = threadIdx.x;
    const int lane = T & 63, wid = T >> 6;
    const int wr = wid >> 2, wc = wid & 3;          // wave -> (2 x 4) grid
    const int fr = lane & 15, fq = lane >> 4;
    const int laneoff = fr * 64 + ((fq * 16) ^ ((fr >> 3) << 5));   // swz read

    // read bases (per buf): A region at +0, B region at +32768 within a buf
    const char* pA0 = smem + 0     + wr * 8192 + laneoff;
    const char* pB0 = smem + 32768 + wc * 4096 + laneoff;
    const char* pA1 = pA0 + 65536;
    const char* pB1 = pB0 + 65536;

    // staging: thread T stages bytes [T*16,T*16+16) of each 8KB load-slice;
    // source col pre-swizzled (involution) so linear LDS dest + swz read match.
    const int s_row = T >> 2;                                   // 0..127
    const int s_csw = ((T & 3) * 16) ^ (((T >> 5) & 1) << 5);   // pre-swz col byte
    const ushort* gA = A + (size_t)(bm0 + s_row) * K + (s_csw >> 1);
    const ushort* gB = B + (size_t)(bn0 + s_row) * K + (s_csw >> 1);

    const int nt = K >> 6;      // K-steps of 64 (even, >= 4 here)

    // stage one half-tile (op, kh) of step snext into buf db (2 loads/thread)
    auto stage = [&](int op, int kh, int db, int snext) {
        const ushort* g = op ? gB : gA;
        const size_t kbase = (size_t)snext * 64 + kh * 32;
        char* d = smem + db * 65536 + op * 32768 + kh * 16384 + (T << 4);
#pragma unroll
        for (int j = 0; j < 2; ++j) {
            __builtin_amdgcn_global_load_lds(
                (const __attribute__((address_space(1))) void*)(g + (size_t)j * 128 * K + kbase),
                (__attribute__((address_space(3))) void*)(d + j * 8192), 16, 0, 0);
        }
    };

    f32x4 acc[8][4];
#pragma unroll
    for (int m = 0; m < 8; ++m)
#pragma unroll
        for (int n = 0; n < 4; ++n)
#pragma unroll
            for (int j = 0; j < 4; ++j) acc[m][n][j] = 0.f;

    // one phase.  MH,KH: quadrant.  RDB: load b-frags.  SOP/SKH: stage half-tile
    // (if DOST).  VM: -1 none / 4 counted / 0 drain.
    auto phase = [&](const char* pA, const char* pB, short8* bfr, int s, int db,
                     auto MH, auto KH, auto RDB, auto DOST, auto SOP, auto SKH, auto VM) {
        constexpr int mh = decltype(MH)::v, kh = decltype(KH)::v;
        short8 a[4];
#pragma unroll
        for (int i = 0; i < 4; ++i)
            a[i] = *(const short8*)(pA + kh * 16384 + (mh * 4 + i) * 1024);
        if constexpr (decltype(RDB)::v) {
#pragma unroll
            for (int n = 0; n < 4; ++n)
                bfr[n] = *(const short8*)(pB + kh * 16384 + n * 1024);
        }
        if constexpr (decltype(DOST)::v)
            stage(decltype(SOP)::v, decltype(SKH)::v, db ^ 1, s + 1);
        asm volatile("s_barrier" ::: "memory");
        asm volatile("s_waitcnt lgkmcnt(0)" ::: "memory");
        __builtin_amdgcn_sched_barrier(0);
        __builtin_amdgcn_s_setprio(1);
#pragma unroll
        for (int i = 0; i < 4; ++i)
#pragma unroll
            for (int n = 0; n < 4; ++n)
                acc[mh * 4 + i][n] = __builtin_amdgcn_mfma_f32_16x16x32_bf16(
                    a[i], bfr[n], acc[mh * 4 + i][n], 0, 0, 0);
        __builtin_amdgcn_s_setprio(0);
        __builtin_amdgcn_sched_barrier(0);
        constexpr int vm = decltype(VM)::v;
        if constexpr (vm == 4) asm volatile("s_waitcnt vmcnt(4)" ::: "memory");
        else if constexpr (vm == 0) asm volatile("s_waitcnt vmcnt(0)" ::: "memory");
        asm volatile("s_barrier" ::: "memory");
    };

    auto step_full = [&](int s, const char* pA, const char* pB, int db) {
        short8 bfr[4];
        phase(pA, pB, bfr, s, db, IC<0>{}, IC<0>{}, IC<1>{}, IC<1>{}, IC<0>{}, IC<0>{}, IC<-1>{});
        phase(pA, pB, bfr, s, db, IC<1>{}, IC<0>{}, IC<0>{}, IC<1>{}, IC<1>{}, IC<0>{}, IC<4>{});
        phase(pA, pB, bfr, s, db, IC<0>{}, IC<1>{}, IC<1>{}, IC<1>{}, IC<0>{}, IC<1>{}, IC<-1>{});
        phase(pA, pB, bfr, s, db, IC<1>{}, IC<1>{}, IC<0>{}, IC<1>{}, IC<1>{}, IC<1>{}, IC<4>{});
    };
    auto step_last = [&](int s, const char* pA, const char* pB, int db) {
        short8 bfr[4];
        phase(pA, pB, bfr, s, db, IC<0>{}, IC<0>{}, IC<1>{}, IC<0>{}, IC<0>{}, IC<0>{}, IC<-1>{});
        phase(pA, pB, bfr, s, db, IC<1>{}, IC<0>{}, IC<0>{}, IC<0>{}, IC<0>{}, IC<0>{}, IC<0>{});
        phase(pA, pB, bfr, s, db, IC<0>{}, IC<1>{}, IC<1>{}, IC<0>{}, IC<0>{}, IC<0>{}, IC<-1>{});
        phase(pA, pB, bfr, s, db, IC<1>{}, IC<1>{}, IC<0>{}, IC<0>{}, IC<0>{}, IC<0>{}, IC<-1>{});
    };

    // prologue: stage step 0 (stream order A.k0,B.k0,A.k1,B.k1) into buf0;
    // vmcnt(4) -> k0 halves landed (k1 lands under P0/P1, guarded by P1's vmcnt)
    stage(0, 0, 0, 0); stage(1, 0, 0, 0); stage(0, 1, 0, 0); stage(1, 1, 0, 0);
    asm volatile("s_waitcnt vmcnt(4)" ::: "memory");
    asm volatile("s_barrier" ::: "memory");

    for (int s = 0; s < nt - 2; s += 2) {
        step_full(s,     pA0, pB0, 0);
        step_full(s + 1, pA1, pB1, 1);
    }
    step_full(nt - 2, pA0, pB0, 0);   // stages step nt-1 into buf1
    step_last(nt - 1, pA1, pB1, 1);

    // epilogue: C[row = m*16 + fq*4 + j][col = n*16 + fr]  (m89/m91-verified)
    ushort* C = Cout + (size_t)z * sC_z;
    const int row0 = bm0 + wr * 128;
    const int col0 = bn0 + wc * 64;
#pragma unroll
    for (int n = 0; n < 4; ++n) {
        const int c = col0 + n * 16 + fr;
        const float bvv = biasp ? biasp[c] : 0.f;
#pragma unroll
        for (int m = 0; m < 8; ++m) {
            const int r = row0 + m * 16 + fq * 4;
#pragma unroll
            for (int j = 0; j < 4; ++j) {
                float val = acc[m][n][j] + bvv;
                if (RELU) val = fmaxf(val, 0.f);
                C[(size_t)(r + j) * ldc + c] = f2bf(val);
            }
        }
    }
}

// ---------------- in-place LayerNorm over last dim (1024) of agg bf16 --------
__global__ __launch_bounds__(256) void ln_kernel(ushort* __restrict__ agg,
                                                 const float* __restrict__ gamma,
                                                 const float* __restrict__ beta) {
    const int wid = threadIdx.x >> 6, lane = threadIdx.x & 63;
    const size_t row = (size_t)blockIdx.x * 4 + wid;
    const int h = (int)(row >> 12);
    ushort* p = agg + row * 1024 + lane * 16;
    short8 r0 = *(const short8*)p;
    short8 r1 = *(const short8*)(p + 8);
    float x[16];
#pragma unroll
    for (int j = 0; j < 8; ++j) { x[j] = bf2f((ushort)r0[j]); x[8 + j] = bf2f((ushort)r1[j]); }
    float s = 0.f, s2 = 0.f;
#pragma unroll
    for (int j = 0; j < 16; ++j) { s += x[j]; s2 += x[j] * x[j]; }
    for (int o = 1; o < 64; o <<= 1) {
        s  += __shfl_xor(s,  o, 64);
        s2 += __shfl_xor(s2, o, 64);
    }
    float mu  = s * (1.0f / 1024.0f);
    float var = s2 * (1.0f / 1024.0f) - mu * mu;
    float rs  = rsqrtf(fmaxf(var, 0.f) + 1e-5f);
    const float* g  = gamma + (size_t)h * 1024 + lane * 16;
    const float* bt = beta  + (size_t)h * 1024 + lane * 16;
    short8 o0, o1;
#pragma unroll
    for (int j = 0; j < 8; ++j) {
        o0[j] = (short)f2bf((x[j]     - mu) * rs * g[j]     + bt[j]);
        o1[j] = (short)f2bf((x[8 + j] - mu) * rs * g[8 + j] + bt[8 + j]);
    }
    *(short8*)p = o0;
    *(short8*)(p + 8) = o1;
}

// ---------------- projection: out[b][q][(h0+h)*64+e] = normed[z] @ WpT[h]^T + bp
__global__ __launch_bounds__(256) void proj_kernel(const ushort* __restrict__ normed,
                                                   const ushort* __restrict__ WpT,
                                                   const float* __restrict__ bp,
                                                   float* __restrict__ out,
                                                   int h_base) {
    const int z = blockIdx.y, b = z & 1, h = z >> 1;
    const int hg = h_base + h;
    const int wid = threadIdx.x >> 6, lane = threadIdx.x & 63;
    const int fr = lane & 15, fq = lane >> 4;
    const int m0 = (blockIdx.x * 4 + wid) * 16;

    const ushort* Abase = normed + ((size_t)z * 2048 + m0 + fr) * 1024 + fq * 8;
    const ushort* Bbase = WpT + (size_t)hg * 64 * 1024 + (size_t)fr * 1024 + fq * 8;

    f32x4 acc[4];
#pragma unroll
    for (int n = 0; n < 4; ++n)
#pragma unroll
        for (int j = 0; j < 4; ++j) acc[n][j] = 0.f;

    for (int kt = 0; kt < 32; ++kt) {
        short8 a = *(const short8*)(Abase + kt * 32);
#pragma unroll
        for (int n = 0; n < 4; ++n) {
            short8 bb = *(const short8*)(Bbase + n * 16 * 1024 + kt * 32);
            acc[n] = __builtin_amdgcn_mfma_f32_16x16x32_bf16(a, bb, acc[n], 0, 0, 0);
        }
    }
#pragma unroll
    for (int n = 0; n < 4; ++n) {
        int c = hg * 64 + n * 16 + fr;
        float bvv = bp[hg * 64 + n * 16 + fr];
#pragma unroll
        for (int j = 0; j < 4; ++j)
            out[(size_t)b * 2048 * 1024 + (size_t)(m0 + fq * 4 + j) * 1024 + c] =
                acc[n][j] + bvv;
    }
}

extern "C" void kernel_launch(void* const* d_in, const int* in_sizes, int n_in,
                              void* d_out, int out_size, void* d_ws, size_t ws_size,
                              hipStream_t stream) {
    const float* v     = (const float*)d_in[0];
    const float* q     = (const float*)d_in[1];
    const float* Wa    = (const float*)d_in[2];
    const float* ba    = (const float*)d_in[3];
    const float* gamma = (const float*)d_in[4];
    const float* beta  = (const float*)d_in[5];
    const float* Wp    = (const float*)d_in[6];
    const float* bp    = (const float*)d_in[7];
    float* out = (float*)d_out;

    const size_t MB = 1ull << 20;
    char* ws = (char*)d_ws;
    ushort* qbf = (ushort*)(ws);                 //  8 MiB
    ushort* vT  = (ushort*)(ws + 8 * MB);        //  8 MiB
    ushort* WpT = (ushort*)(ws + 16 * MB);       //  2 MiB
    int NH = 1;
    {
        const int cands[5] = {16, 8, 4, 2, 1};
        for (int i = 0; i < 5; ++i) {
            if ((size_t)(18 + 28 * cands[i]) * MB <= ws_size) { NH = cands[i]; break; }
        }
    }
    ushort* WaT_c  = (ushort*)(ws + 18 * MB);
    ushort* attn_c = (ushort*)(ws + (18 + (size_t)4 * NH) * MB);
    ushort* agg_c  = (ushort*)(ws + (18 + (size_t)20 * NH) * MB);

    dim3 tb(32, 8);
    cast_bf16<<<4096, 256, 0, stream>>>(q, qbf, BATCH * LQ * DMODEL);
    transpose_cast<<<dim3(DMODEL / 32, LV / 32, BATCH), tb, 0, stream>>>(v, vT, LV, DMODEL);
    transpose_cast<<<dim3(HEAD_DIM / 32, DMODEL / 32, N_HEAD), tb, 0, stream>>>(Wp, WpT, DMODEL, HEAD_DIM);

    for (int h0 = 0; h0 < N_HEAD; h0 += NH) {
        transpose_cast<<<dim3(LV / 32, DMODEL / 32, NH), tb, 0, stream>>>(
            Wa + (size_t)h0 * DMODEL * LV, WaT_c, DMODEL, LV);

        // GEMM1: attn[z] = relu(q[b] @ WaT[h]^T + ba[h0+h]), M=2048 N=2048 K=1024
        gemm256<true><<<dim3(LV / 256, LQ / 256, NH * 2), 512, 0, stream>>>(
            qbf, WaT_c, attn_c, ba + (size_t)h0 * LV, DMODEL,
            (long)LQ * DMODEL, 0L,
            0L, (long)LV * DMODEL,
            (long)LQ * LV, LV, (long)LV);

        // GEMM2: agg[z] = attn[z] @ vT[b]^T, M=2048 N=1024 K=2048
        gemm256<false><<<dim3(DMODEL / 256, LQ / 256, NH * 2), 512, 0, stream>>>(
            attn_c, vT, agg_c, nullptr, LV,
            (long)LQ * LV, (long)2 * LQ * LV,
            (long)DMODEL * LV, 0L,
            (long)LQ * DMODEL, DMODEL, 0L);

        ln_kernel<<<(NH * 2 * LQ) / 4, 256, 0, stream>>>(
            agg_c, gamma + (size_t)h0 * DMODEL, beta + (size_t)h0 * DMODEL);

        proj_kernel<<<dim3(LQ / 64, NH * 2), 256, 0, stream>>>(
            agg_c, WpT, bp, out, h0);
    }
}